// Round 5
// baseline (179.763 us; speedup 1.0000x reference)
//
#include <hip/hip_runtime.h>
#include <hip/hip_bf16.h>
#include <stdint.h>

typedef uint32_t u32;
typedef uint64_t u64;
typedef __bf16 bf16x8 __attribute__((ext_vector_type(8)));
typedef float f32x4 __attribute__((ext_vector_type(4)));
typedef u32 u32x4 __attribute__((ext_vector_type(4)));

#define NB 8
#define NN 2048
#define DIN 256
#define DOUT 256
#define NR 4
#define KTOT (NN * NR)  // 8192

// ws layout
#define XW_BYTES   (NB * DOUT * KTOT * 2)          // 33,554,432
#define PART_BYTES (NB * NN * DOUT * 4)            // 16,777,216

__device__ __forceinline__ ushort f2bf(float f) {
  union { float f; u32 u; } c; c.f = f;
  return (ushort)((c.u + 0x7FFFu + ((c.u >> 16) & 1u)) >> 16);
}

__device__ __forceinline__ void gload_lds16(const void* g, void* l) {
  __builtin_amdgcn_global_load_lds(
      (const __attribute__((address_space(1))) u32*)g,
      (__attribute__((address_space(3))) u32*)l, 16, 0, 0);
}

// ---------------- kernel 0: wT[r][o][d] = bf16(w[r][d][o]) ----------------
__global__ void k0_wT(const float* __restrict__ w, ushort* __restrict__ wT) {
  int i = blockIdx.x * 256 + threadIdx.x;   // 262144 total
  int o = i & 255, d = (i >> 8) & 255, r = i >> 16;
  wT[(r * DOUT + o) * DIN + d] = f2bf(w[i]);
}

// ---------------- kernel 1: xwT[b][o][m*4+r] = bf16(x[b,m,:]@W[r][:,o]) ----
__global__ __launch_bounds__(512) void k1_xw(const float* __restrict__ x,
                                             const ushort* __restrict__ wT,
                                             ushort* __restrict__ xwT) {
  __shared__ char smem[65536];
  ushort* As = (ushort*)smem;           // [64 m][32 d]
  ushort* Bs = (ushort*)(smem + 4096);  // [4 r][128 o][32 d]
  const int t = threadIdx.x, l = t & 63, w = t >> 6;
  const int r = w >> 1, oh = w & 1;
  const int blk = blockIdx.x;
  const int b = blk >> 6, rest = blk & 63, mc = rest >> 1, ot = rest & 1;

  f32x4 acc[4][4] = {};
  const int arow = t >> 3, adc = (t & 7) << 2;
  const float* xg = x + ((size_t)(b * NN + mc * 64 + arow) * DIN + adc);

  for (int s = 0; s < 8; ++s) {
    const int d0 = s * 32;
    float4 xv = *(const float4*)(xg + d0);
    ushort4 a4;
    a4.x = f2bf(xv.x); a4.y = f2bf(xv.y); a4.z = f2bf(xv.z); a4.w = f2bf(xv.w);
    *(ushort4*)(As + arow * 32 + adc) = a4;
#pragma unroll
    for (int i = 0; i < 4; ++i) {
      int off = i * 4096 + t * 8;
      int rr = off >> 12, rem = off & 4095, o = rem >> 5, dd = rem & 31;
      const ushort* src = wT + ((size_t)(rr * DOUT + ot * 128 + o) * DIN + d0 + dd);
      gload_lds16(src, Bs + off);
    }
    __syncthreads();
    bf16x8 af[4];
#pragma unroll
    for (int fm = 0; fm < 4; ++fm)
      af[fm] = *(const bf16x8*)(As + (fm * 16 + (l & 15)) * 32 + (l >> 4) * 8);
#pragma unroll
    for (int fo = 0; fo < 4; ++fo) {
      bf16x8 bf = *(const bf16x8*)(Bs + (size_t)(r * 128 + oh * 64 + fo * 16 + (l & 15)) * 32 + (l >> 4) * 8);
#pragma unroll
      for (int fm = 0; fm < 4; ++fm)
        acc[fm][fo] = __builtin_amdgcn_mfma_f32_16x16x32_bf16(af[fm], bf, acc[fm][fo], 0, 0, 0);
    }
    __syncthreads();
  }
  ushort* Cs = (ushort*)smem;
#pragma unroll
  for (int fm = 0; fm < 4; ++fm)
#pragma unroll
    for (int fo = 0; fo < 4; ++fo)
#pragma unroll
      for (int j = 0; j < 4; ++j) {
        int o_loc = oh * 64 + fo * 16 + (l & 15);
        int ml = fm * 16 + (l >> 4) * 4 + j;
        Cs[o_loc * 256 + ml * 4 + r] = f2bf(acc[fm][fo][j]);
      }
  __syncthreads();
#pragma unroll
  for (int i = 0; i < 8; ++i) {
    int el = (i * 512 + t) * 8;
    int o_loc = el >> 8, kp = el & 255;
    *(uint4*)(xwT + (size_t)(b * DOUT + ot * 128 + o_loc) * KTOT + mc * 256 + kp) =
        *(const uint4*)(Cs + el);
  }
}

// ---------------- kernel 2: one-hot GEMM, B direct-to-reg, A-only LDS -----
// grid 512 logical: b.nt.ks.ot, XCD-swizzled (each XCD owns one b).
// 256 thr = 4 waves (2x2), wave 64x64, 4x4 frags 16x16x32, BK=64.
// LDS 32KB: A dbuf only (one-hot expand, XOR-swz). B fragments are loaded
// straight from xwT (o-major; frag = 16B contiguous) into registers,
// prefetch distance 1. Barrier = lgkmcnt(0) + s_barrier ONLY — no vmcnt:
// all global loads are register-destined and compiler-tracked, so B/rel
// prefetch stays in flight across the barrier, hidden under MFMA.
__global__ __launch_bounds__(256, 2) void k2_main(const int* __restrict__ rel,
                                                  const ushort* __restrict__ xwT,
                                                  float* __restrict__ out,
                                                  float* __restrict__ part) {
  __shared__ char smem[32768];
  const int t = threadIdx.x, l = t & 63, w = t >> 6;
  const int wr = w >> 1, wc = w & 1;
  const int logical = (blockIdx.x & 7) * 64 + (blockIdx.x >> 3);
  const int b = logical >> 6;
  const int nt = (logical >> 2) & 15;
  const int ks = (logical >> 1) & 1;
  const int ot = logical & 1;

  f32x4 acc[4][4] = {};
  const int arow = t >> 1, half = t & 1;
  const int* relg = rel + ((size_t)(b * NN + nt * 128 + arow) * NN + ks * 1024 + half * 8);

  char* const Ab0 = smem;
  char* const Ab1 = smem + 16384;

  const int aswz = (arow & 7) << 4;
  const int fr = l & 15, fq = l >> 4;
  const int rswz = (fr & 7) << 4;

  // B direct: lane base row o = ot*128 + wc*64 + fr, k base = ks*4096 + fq*8
  const ushort* xwp = xwT + (size_t)(b * DOUT + ot * 128 + wc * 64 + fr) * KTOT +
                      ks * 4096 + fq * 8;

  bf16x8 bv0[8], bv1[8];        // frag sets, parity = step&1; idx = kk*4+fo
  int4 rsA0, rsB0, rsA1, rsB1;  // rel prefetch, parity sets

#define LOADB(BV, S)                                                           \
  _Pragma("unroll") for (int ff = 0; ff < 8; ++ff) {                           \
    const int fo_ = ff & 3, kk_ = ff >> 2;                                     \
    BV[ff] = *(const bf16x8*)(xwp + (size_t)fo_ * 16 * KTOT + (S) * 64 + kk_ * 32); \
  }

#define RELLOAD(S, RA, RB)                                                     \
  RA = *(const int4*)(relg + (S) * 16);                                        \
  RB = *(const int4*)(relg + (S) * 16 + 4);

#define EXPAND_A(ABASE, V0, V1)                                                \
  {                                                                            \
    char* rowp = (ABASE) + arow * 128;                                         \
    int vv[8] = {V0.x, V0.y, V0.z, V0.w, V1.x, V1.y, V1.z, V1.w};              \
    _Pragma("unroll") for (int p = 0; p < 4; ++p) {                            \
      int va = vv[2 * p], vb = vv[2 * p + 1];                                  \
      u32 sa = ((u32)(va - 1) & 3u) * 16u;                                     \
      u32 sb = ((u32)(vb - 1) & 3u) * 16u;                                     \
      u64 ha = va ? (0x3F80ull << sa) : 0ull;                                  \
      u64 hb = vb ? (0x3F80ull << sb) : 0ull;                                  \
      u32x4 e = {(u32)ha, (u32)(ha >> 32), (u32)hb, (u32)(hb >> 32)};          \
      *(u32x4*)(rowp + ((half * 64 + p * 16) ^ aswz)) = e;                     \
    }                                                                          \
  }

#define BAR()                                                                  \
  asm volatile("s_waitcnt lgkmcnt(0)" ::: "memory");                           \
  __builtin_amdgcn_s_barrier();                                                \
  __builtin_amdgcn_sched_barrier(0);

#define MFMA_STEP(AC, BV)                                                      \
  __builtin_amdgcn_s_setprio(1);                                               \
  _Pragma("unroll") for (int kk = 0; kk < 2; ++kk) {                           \
    bf16x8 af[4];                                                              \
    const int colb = (kk * 64 + fq * 16) ^ rswz;                               \
    _Pragma("unroll") for (int fm = 0; fm < 4; ++fm)                           \
      af[fm] = *(const bf16x8*)((AC) + (wr * 64 + fm * 16 + fr) * 128 + colb); \
    _Pragma("unroll") for (int fm = 0; fm < 4; ++fm)                           \
      _Pragma("unroll") for (int fo = 0; fo < 4; ++fo)                         \
        acc[fm][fo] = __builtin_amdgcn_mfma_f32_16x16x32_bf16(                 \
            af[fm], BV[kk * 4 + fo], acc[fm][fo], 0, 0, 0);                    \
  }                                                                            \
  __builtin_amdgcn_s_setprio(0);

// body(S), P = S&1, Q = 1-P: prefetch B(S+1)->bvQ, rel(S+2)->rsP,
// MFMA(S) from AbP+bvP, expand A(S+1) from rsQ into AbQ, barrier.
#define BODY(S, P, Q)                                                          \
  {                                                                            \
    LOADB(bv##Q, (S) + 1);                                                     \
    RELLOAD((S) + 2, rsA##P, rsB##P);                                          \
    MFMA_STEP(Ab##P, bv##P);                                                   \
    EXPAND_A(Ab##Q, rsA##Q, rsB##Q);                                           \
    BAR();                                                                     \
  }

  // prologue: rel(0)->rs0, rel(1)->rs1, B(0)->bv0, expand A(0)
  RELLOAD(0, rsA0, rsB0);
  RELLOAD(1, rsA1, rsB1);
  LOADB(bv0, 0);
  EXPAND_A(Ab0, rsA0, rsB0);
  BAR();

  for (int s = 0; s < 62; s += 2) {
    BODY(s, 0, 1);
    BODY(s + 1, 1, 0);
  }
  {  // s = 62: no rel prefetch
    LOADB(bv1, 63);
    MFMA_STEP(Ab0, bv0);
    EXPAND_A(Ab1, rsA1, rsB1);
    BAR();
  }
  {  // s = 63
    MFMA_STEP(Ab1, bv1);
  }

  float* dst = ks ? part : out;
#pragma unroll
  for (int fm = 0; fm < 4; ++fm)
#pragma unroll
    for (int fo = 0; fo < 4; ++fo) {
      int n = nt * 128 + wr * 64 + fm * 16 + fq * 4;
      int o = ot * 128 + wc * 64 + fo * 16 + fr;
#pragma unroll
      for (int j = 0; j < 4; ++j)
        dst[(size_t)(b * NN + n + j) * DOUT + o] = acc[fm][fo][j];
    }
#undef BODY
#undef MFMA_STEP
#undef BAR
#undef EXPAND_A
#undef RELLOAD
#undef LOADB
}

// ---------------- kernel 3: out = out(ks0) + part(ks1) + bias --------------
__global__ void k3_add(float* __restrict__ out, const float* __restrict__ part,
                       const float* __restrict__ bias) {
  int i = blockIdx.x * 256 + threadIdx.x;  // float4 index, 1048576 total
  float4 o = ((const float4*)out)[i];
  float4 p = ((const float4*)part)[i];
  float4 bv = ((const float4*)bias)[i & 63];
  float4 rr;
  rr.x = o.x + p.x + bv.x;
  rr.y = o.y + p.y + bv.y;
  rr.z = o.z + p.z + bv.z;
  rr.w = o.w + p.w + bv.w;
  ((float4*)out)[i] = rr;
}

extern "C" void kernel_launch(void* const* d_in, const int* in_sizes, int n_in,
                              void* d_out, int out_size, void* d_ws, size_t ws_size,
                              hipStream_t stream) {
  const float* x = (const float*)d_in[0];
  const int* rel = (const int*)d_in[2];
  const float* wgt = (const float*)d_in[3];
  const float* bias = (const float*)d_in[4];
  float* out = (float*)d_out;
  char* ws = (char*)d_ws;

  ushort* xwT = (ushort*)ws;                                 // 32 MiB
  float* part = (float*)(ws + XW_BYTES);                     // 16 MiB
  ushort* wT = (ushort*)(ws + XW_BYTES + PART_BYTES);        // 0.5 MiB

  k0_wT<<<1024, 256, 0, stream>>>(wgt, wT);
  k1_xw<<<512, 512, 0, stream>>>(x, wT, xwT);
  k2_main<<<512, 256, 0, stream>>>(rel, xwT, out, part);
  k3_add<<<4096, 256, 0, stream>>>(out, part, bias);
}